// Round 9
// baseline (375.717 us; speedup 1.0000x reference)
//
#include <hip/hip_runtime.h>

// GraphSAGE link predictor, bf16-MFMA edition.
//   h = relu( mean_agg(x)@w1l.T + b1 + x@w1r.T )
//   z = mean_agg(h)@w2l.T + b2 + h@w2r.T
//   out[e] = dot(z[src[e]], z[dst[e]])
//
// R7-R12: padded-CSR scatter builds all bottomed at ~70-86us on scattered
//     4B store amplification (WRITE 59-65MB for 6.4MB useful).
// R13: counting-sort CSR (bucket 256 fine dst-ranges -> LDS counting sort ->
//     dense copy-out). Build off the top-5. 399 -> 372.5us.
// R14: top kernel now agg_bf L1 (73us, FETCH 180MB, 2.9TB/s, VALU 22%).
//     Memory floor ~35-40us; suspect the per-node serial chain: deg~16 done
//     as 4 DEPENDENT rounds of 4 gathers. Group 8-deep (2 rounds) to double
//     in-flight gathers per node. Single-variable experiment: if neutral,
//     agg is at the random-gather roofline.
//
// edge_index arrives as int32 (harness converts int64 inputs).

#define IN_C      128
#define HID_C     128
#define OUT_C     64
#define NB        256    // fine dst-range buckets (nr2 = ceil(N/NB) = 391 <= 512)
#define NREP      8      // replicas per bucket; rep = blockIdx&7 = XCD id
#define CSTRIDE   16     // ints per cursor slot (64B line, no false sharing)
#define SUBCAP1   1024   // entries per (bucket,rep); mean ~784, +8 sigma
#define SORTG     8192   // global slots per bucket (mean 6250, +24 sigma)
#define SSORT     7168   // LDS sort buffer ints (28 KB)
#define EPB       1024   // phase-1 edges per block

typedef unsigned short u16;
typedef __attribute__((ext_vector_type(8))) __bf16 bf16x8;
typedef __attribute__((ext_vector_type(4))) float f32x4;
typedef __attribute__((ext_vector_type(4))) int i32x4;
typedef __attribute__((ext_vector_type(2))) int i32x2;

__device__ inline u16 f2bf(float f) {                 // RNE f32 -> bf16
    unsigned u = __float_as_uint(f);
    u += 0x7fff + ((u >> 16) & 1);
    return (u16)(u >> 16);
}
__device__ inline float bflo(unsigned v) { return __uint_as_float(v << 16); }
__device__ inline float bfhi(unsigned v) { return __uint_as_float(v & 0xffff0000u); }

// ---------------------------------------------------------------- phase 1: bucket
// Block-radix partition into NB fine dst-range buckets, XCD-private cursors.
__global__ __launch_bounds__(256) void bucket_edges(const int* __restrict__ ei,
                                                    int* __restrict__ bcur,
                                                    i32x2* __restrict__ bkt,
                                                    int E, int n, int nr2) {
    __shared__ int hist[NB];
    __shared__ int gofs[NB];
    const int tid = threadIdx.x;
    hist[tid] = 0;
    __syncthreads();

    const int rep  = blockIdx.x & (NREP - 1);   // == XCD id (round-robin dispatch)
    const int base = blockIdx.x * EPB + tid * 4;

    i32x4 d4 = {-1, -1, -1, -1}, s4 = {0, 0, 0, 0};
    if (base < E) {   // base%4==0, E%4==0 => full int4 in bounds
        d4 = __builtin_nontemporal_load((const i32x4*)(ei + (size_t)E + base));
        s4 = __builtin_nontemporal_load((const i32x4*)(ei + base));
    }

    int bk[4], rk[4];
#pragma unroll
    for (int j = 0; j < 4; ++j) {
        int d = d4[j], s = s4[j];
        bk[j] = ((unsigned)d < (unsigned)n && (unsigned)s < (unsigned)n)
                    ? (int)((unsigned)d / (unsigned)nr2) : -1;
        if (bk[j] >= 0) rk[j] = atomicAdd(&hist[bk[j]], 1);   // LDS atomic
    }
    __syncthreads();
    // one 64B-private cursor per (bucket,rep): only XCD `rep` ever touches it.
    gofs[tid] = atomicAdd(&bcur[(tid * NREP + rep) * CSTRIDE], hist[tid]);
    __syncthreads();

#pragma unroll
    for (int j = 0; j < 4; ++j) {
        int b = bk[j];
        if (b >= 0) {
            int pos = gofs[b] + rk[j];
            if (pos < SUBCAP1) {
                i32x2 v; v.x = s4[j]; v.y = d4[j];
                bkt[(size_t)(b * NREP + rep) * SUBCAP1 + pos] = v;
            }
        }
    }
}

// ---------------------------------------------------------------- phase 2: sort
// One block per bucket: LDS counting sort -> dense CSR run + row_start/deg.
__global__ __launch_bounds__(512) void sort_bucket(const i32x2* __restrict__ bkt,
                                                   const int* __restrict__ bcur,
                                                   int* __restrict__ csr_sorted,
                                                   int* __restrict__ row_start,
                                                   int* __restrict__ degp,
                                                   float* __restrict__ inv_deg,
                                                   int n, int nr2) {
    __shared__ int hist[512];
    __shared__ int scanb[512];
    __shared__ int cursor[512];
    __shared__ int ssz[NREP];
    __shared__ int sorted[SSORT];

    const int b   = blockIdx.x;
    const int tid = threadIdx.x;
    const int r0  = b * nr2;
    hist[tid] = 0;
    if (tid < NREP) ssz[tid] = min(bcur[(b * NREP + tid) * CSTRIDE], SUBCAP1);
    __syncthreads();

    // pass A: histogram over local nodes
    for (int r = 0; r < NREP; ++r) {
        const i32x2* sp = bkt + (size_t)(b * NREP + r) * SUBCAP1;
        const int m = ssz[r];
        for (int i = tid; i < m; i += 512)
            atomicAdd(&hist[sp[i].y - r0], 1);
    }
    __syncthreads();

    // inclusive Hillis-Steele scan over 512 slots
    int v = hist[tid];
    scanb[tid] = v;
    __syncthreads();
    for (int off = 1; off < 512; off <<= 1) {
        int add = (tid >= off) ? scanb[tid - off] : 0;
        __syncthreads();
        scanb[tid] += add;
        __syncthreads();
    }
    const int excl = scanb[tid] - v;
    cursor[tid] = excl;
    const int node = r0 + tid;
    if (tid < nr2 && node < n) {
        row_start[node] = b * SORTG + excl;
        degp[node]      = v;
        inv_deg[node]   = 1.0f / (float)max(v, 1);
    }
    __syncthreads();

    // pass B: LDS scatter of src ids into sorted order
    for (int r = 0; r < NREP; ++r) {
        const i32x2* sp = bkt + (size_t)(b * NREP + r) * SUBCAP1;
        const int m = ssz[r];
        for (int i = tid; i < m; i += 512) {
            i32x2 e = sp[i];
            int pos = atomicAdd(&cursor[e.y - r0], 1);
            if (pos < SSORT) sorted[pos] = e.x;
        }
    }
    __syncthreads();

    // dense coalesced copy-out
    const int T = min(scanb[511], SSORT);
    int* dst = csr_sorted + (size_t)b * SORTG;
    for (int i = tid; i < T; i += 512) dst[i] = sorted[i];
}

// ---------------------------------------------------------------- converts
__global__ __launch_bounds__(256) void cvt_x(const float* __restrict__ in,
                                             u16* __restrict__ outb, int n4) {
    int i = blockIdx.x * 256 + threadIdx.x;
    if (i >= n4) return;
    float4 v = ((const float4*)in)[i];
    ushort4 o;
    o.x = f2bf(v.x); o.y = f2bf(v.y); o.z = f2bf(v.z); o.w = f2bf(v.w);
    ((ushort4*)outb)[i] = o;
}

// Wb1[c][0:128]=w1l[c], Wb1[c][128:256]=w1r[c]  -> [128][256] bf16
// Wb2 = cat(w2l,w2r)                             -> [128][128] bf16
__global__ __launch_bounds__(256) void cvt_w(const float* __restrict__ w1l,
                                             const float* __restrict__ w1r,
                                             const float* __restrict__ w2l,
                                             const float* __restrict__ w2r,
                                             u16* __restrict__ Wb1,
                                             u16* __restrict__ Wb2) {
    int i = blockIdx.x * 256 + threadIdx.x;
    if (i < 32768) {
        int c = i >> 8, k = i & 255;
        float v = (k < 128) ? w1l[c * 128 + k] : w1r[c * 128 + (k - 128)];
        Wb1[i] = f2bf(v);
    } else if (i < 49152) {
        int j = i - 32768;
        float v = (j < 8192) ? w2l[j] : w2r[j - 8192];
        Wb2[j] = f2bf(v);
    }
}

// ---------------------------------------------------------------- fused layer-1 GEMM
// h = relu([A0|A1] @ W.T + b), A0/A1 [n][128] bf16, W [128][256] bf16 -> h [n][128] bf16
__global__ __launch_bounds__(256) void gemm_l1(const u16* __restrict__ A0,
                                               const u16* __restrict__ A1,
                                               const u16* __restrict__ Wb,
                                               const float* __restrict__ bias,
                                               u16* __restrict__ outp, int nrows) {
    constexpr int K    = 256;
    constexpr int COLS = 128;
    constexpr int KS   = K / 32;             // 8
    constexpr int NCT  = COLS / 16;          // 8
    constexpr int WROW = K + 8;
    __shared__ u16 wl[COLS * WROW];          // 67.6 KB

    const int t = threadIdx.x;
    for (int i = t; i < COLS * (K / 8); i += 256) {
        int r = i >> 5, p = i & 31;
        *(uint4*)&wl[r * WROW + p * 8] = *(const uint4*)&Wb[(size_t)r * K + p * 8];
    }
    __syncthreads();

    const int wv    = t >> 6;
    const int lane  = t & 63;
    const int cl    = lane & 15;
    const int quad  = lane >> 4;
    const int rbase = blockIdx.x * 128 + wv * 32;

    bf16x8 afrag[2][KS];
#pragma unroll
    for (int tile = 0; tile < 2; ++tile) {
        int r = min(rbase + tile * 16 + cl, nrows - 1);
        const u16* s0 = A0 + (size_t)r * 128 + quad * 8;
        const u16* s1 = A1 + (size_t)r * 128 + quad * 8;
#pragma unroll
        for (int ks = 0; ks < 4; ++ks) {
            afrag[tile][ks]     = *(const bf16x8*)(s0 + ks * 32);
            afrag[tile][4 + ks] = *(const bf16x8*)(s1 + ks * 32);
        }
    }

#pragma unroll
    for (int ct = 0; ct < NCT; ++ct) {
        f32x4 acc0 = {0.f, 0.f, 0.f, 0.f};
        f32x4 acc1 = {0.f, 0.f, 0.f, 0.f};
        const u16* wp = &wl[(ct * 16 + cl) * WROW + quad * 8];
#pragma unroll
        for (int ks = 0; ks < KS; ++ks) {
            bf16x8 bfrag = *(const bf16x8*)(wp + ks * 32);
            acc0 = __builtin_amdgcn_mfma_f32_16x16x32_bf16(afrag[0][ks], bfrag, acc0, 0, 0, 0);
            acc1 = __builtin_amdgcn_mfma_f32_16x16x32_bf16(afrag[1][ks], bfrag, acc1, 0, 0, 0);
        }
        int gc = ct * 16 + cl;
        float bv = bias[gc];
#pragma unroll
        for (int tile = 0; tile < 2; ++tile) {
            f32x4 a = tile ? acc1 : acc0;
#pragma unroll
            for (int r = 0; r < 4; ++r) {
                int row = rbase + tile * 16 + quad * 4 + r;
                if (row < nrows)
                    outp[(size_t)row * COLS + gc] = f2bf(fmaxf(a[r] + bv, 0.f));
            }
        }
    }
}

// ---------------------------------------------------------------- dual GEMM (layer 2)
// [outA | outB](bf16) = xb @ Wb.T ; outB += bias. Wb [2*COLS][K] bf16.
template <int K, int COLS>
__global__ __launch_bounds__(256) void gemm_mfma(const u16* __restrict__ xb,
                                                 const u16* __restrict__ Wb,
                                                 const float* __restrict__ bias,
                                                 u16* __restrict__ outA,
                                                 u16* __restrict__ outB,
                                                 int nrows) {
    constexpr int NCOL = 2 * COLS;
    constexpr int NCT  = NCOL / 16;
    constexpr int KS   = K / 32;
    constexpr int WROW = K + 8;
    __shared__ u16 wl[NCOL * WROW];

    const int t = threadIdx.x;
    for (int i = t; i < NCOL * (K / 8); i += 256) {
        int r = i / (K / 8), p = i % (K / 8);
        *(uint4*)&wl[r * WROW + p * 8] = *(const uint4*)&Wb[(size_t)r * K + p * 8];
    }
    __syncthreads();

    const int wv    = t >> 6;
    const int lane  = t & 63;
    const int cl    = lane & 15;
    const int quad  = lane >> 4;
    const int rbase = blockIdx.x * 128 + wv * 32;

    bf16x8 afrag[2][KS];
#pragma unroll
    for (int tile = 0; tile < 2; ++tile) {
        int r = rbase + tile * 16 + cl;
        const u16* src = xb + (size_t)min(r, nrows - 1) * K + quad * 8;
#pragma unroll
        for (int ks = 0; ks < KS; ++ks)
            afrag[tile][ks] = *(const bf16x8*)(src + ks * 32);
    }

#pragma unroll
    for (int ct = 0; ct < NCT; ++ct) {
        f32x4 acc0 = {0.f, 0.f, 0.f, 0.f};
        f32x4 acc1 = {0.f, 0.f, 0.f, 0.f};
        const u16* wp = &wl[(ct * 16 + cl) * WROW + quad * 8];
#pragma unroll
        for (int ks = 0; ks < KS; ++ks) {
            bf16x8 bfrag = *(const bf16x8*)(wp + ks * 32);
            acc0 = __builtin_amdgcn_mfma_f32_16x16x32_bf16(afrag[0][ks], bfrag, acc0, 0, 0, 0);
            acc1 = __builtin_amdgcn_mfma_f32_16x16x32_bf16(afrag[1][ks], bfrag, acc1, 0, 0, 0);
        }
        int gc = ct * 16 + cl;
        bool isA = gc < COLS;
        float bv = isA ? 0.f : bias[gc - COLS];
        u16* dst = isA ? (outA + gc) : (outB + (gc - COLS));
#pragma unroll
        for (int tile = 0; tile < 2; ++tile) {
            f32x4 a = tile ? acc1 : acc0;
#pragma unroll
            for (int r = 0; r < 4; ++r) {
                int row = rbase + tile * 16 + quad * 4 + r;
                if (row < nrows) dst[(size_t)row * COLS] = f2bf(a[r] + bv);
            }
        }
    }
}

// ---------------------------------------------------------------- aggregate
// out[n] = (sum_{s in row} gl[s]) * inv_deg[n]  [+ other[n]] ; bf16 in/out.
// Exact sorted CSR. R14: gathers grouped 8-deep (deg~16 -> 2 rounds) to
// double in-flight loads per node.
template <int C, bool HAS_OTHER>
__global__ __launch_bounds__(256) void agg_bf(const u16* __restrict__ gl,
                                              const u16* __restrict__ other,
                                              const int* __restrict__ row_start,
                                              const int* __restrict__ degp,
                                              const int* __restrict__ csr_sorted,
                                              const float* __restrict__ inv_deg,
                                              u16* __restrict__ outp, int n) {
    constexpr int G = C / 8;                 // lanes per node
    int t = threadIdx.x;
    int node = blockIdx.x * (256 / G) + t / G;
    int l = t % G;
    if (node >= n) return;

    int deg = degp[node];
    const int* sp = csr_sorted + row_start[node];
    float a[8] = {0.f, 0.f, 0.f, 0.f, 0.f, 0.f, 0.f, 0.f};
    const size_t coff = (size_t)l * 8;
    for (int p0 = 0; p0 < deg; p0 += 8) {
        int kmax = min(8, deg - p0);
        int idx[8];
#pragma unroll
        for (int k = 0; k < 8; ++k) idx[k] = (k < kmax) ? sp[p0 + k] : 0;
        uint4 v[8];
#pragma unroll
        for (int k = 0; k < 8; ++k)
            if (k < kmax) v[k] = *(const uint4*)(gl + (size_t)idx[k] * C + coff);
#pragma unroll
        for (int k = 0; k < 8; ++k)
            if (k < kmax) {
                a[0] += bflo(v[k].x); a[1] += bfhi(v[k].x);
                a[2] += bflo(v[k].y); a[3] += bfhi(v[k].y);
                a[4] += bflo(v[k].z); a[5] += bfhi(v[k].z);
                a[6] += bflo(v[k].w); a[7] += bfhi(v[k].w);
            }
    }
    float id = inv_deg[node];
    float r[8];
    if (HAS_OTHER) {
        uint4 o = *(const uint4*)(other + (size_t)node * C + coff);
        r[0] = fmaf(a[0], id, bflo(o.x)); r[1] = fmaf(a[1], id, bfhi(o.x));
        r[2] = fmaf(a[2], id, bflo(o.y)); r[3] = fmaf(a[3], id, bfhi(o.y));
        r[4] = fmaf(a[4], id, bflo(o.z)); r[5] = fmaf(a[5], id, bfhi(o.z));
        r[6] = fmaf(a[6], id, bflo(o.w)); r[7] = fmaf(a[7], id, bfhi(o.w));
    } else {
#pragma unroll
        for (int j = 0; j < 8; ++j) r[j] = a[j] * id;
    }
    uint4 w;
    w.x = (unsigned)f2bf(r[0]) | ((unsigned)f2bf(r[1]) << 16);
    w.y = (unsigned)f2bf(r[2]) | ((unsigned)f2bf(r[3]) << 16);
    w.z = (unsigned)f2bf(r[4]) | ((unsigned)f2bf(r[5]) << 16);
    w.w = (unsigned)f2bf(r[6]) | ((unsigned)f2bf(r[7]) << 16);
    *(uint4*)(outp + (size_t)node * C + coff) = w;
}

// ---------------------------------------------------------------- decode (bf16 z)
__global__ __launch_bounds__(256) void decode(const u16* __restrict__ z,
                                              const int* __restrict__ ei,
                                              float* __restrict__ out, int E, int n) {
    int t = blockIdx.x * 256 + threadIdx.x;
    int e = t >> 3, l = t & 7;
    if (e >= E) return;
    int s = __builtin_nontemporal_load(ei + e);
    int d = __builtin_nontemporal_load(ei + (size_t)E + e);
    float p = 0.f;
    if ((unsigned)s < (unsigned)n && (unsigned)d < (unsigned)n) {
        uint4 a = *(const uint4*)(z + (size_t)s * OUT_C + l * 8);
        uint4 b = *(const uint4*)(z + (size_t)d * OUT_C + l * 8);
        p  = bflo(a.x) * bflo(b.x) + bfhi(a.x) * bfhi(b.x);
        p += bflo(a.y) * bflo(b.y) + bfhi(a.y) * bfhi(b.y);
        p += bflo(a.z) * bflo(b.z) + bfhi(a.z) * bfhi(b.z);
        p += bflo(a.w) * bflo(b.w) + bfhi(a.w) * bfhi(b.w);
    }
    p += __shfl_xor(p, 4);
    p += __shfl_xor(p, 2);
    p += __shfl_xor(p, 1);
    if (l == 0) out[e] = p;
}

// ---------------------------------------------------------------- launch
extern "C" void kernel_launch(void* const* d_in, const int* in_sizes, int n_in,
                              void* d_out, int out_size, void* d_ws, size_t ws_size,
                              hipStream_t stream) {
    const float* x   = (const float*)d_in[0];
    const int*   ei  = (const int*)d_in[1];
    const float* w1l = (const float*)d_in[2];
    const float* w1r = (const float*)d_in[3];
    const float* b1  = (const float*)d_in[4];
    const float* w2l = (const float*)d_in[5];
    const float* w2r = (const float*)d_in[6];
    const float* b2  = (const float*)d_in[7];
    float*       out = (float*)d_out;

    const int N = in_sizes[0] / IN_C;
    const int E = in_sizes[1] / 2;
    const int nr2 = (N + NB - 1) / NB;     // nodes per bucket (391)

    auto alignup = [](size_t v) { return (v + 255) & ~(size_t)255; };
    char* p = (char*)d_ws;
    float* inv_deg    = (float*)p; p += alignup((size_t)N * 4);
    int*   degp       = (int*)p;   p += alignup((size_t)N * 4);
    int*   row_start  = (int*)p;   p += alignup((size_t)N * 4);
    int*   bcur       = (int*)p;   p += alignup((size_t)NB * NREP * CSTRIDE * 4);
    int*   csr_sorted = (int*)p;   p += alignup((size_t)NB * SORTG * 4);           // 8.4 MB
    i32x2* bkt        = (i32x2*)p; p += alignup((size_t)NB * NREP * SUBCAP1 * 8);  // 16.8 MB
    u16*   Wb1        = (u16*)p;   p += alignup((size_t)HID_C * 2 * IN_C * 2);
    u16*   Wb2        = (u16*)p;   p += alignup((size_t)2 * OUT_C * HID_C * 2);
    u16*   xb         = (u16*)p;   p += alignup((size_t)N * IN_C * 2);  // dead after gemm_l1
    u16*   ag1        = (u16*)p;   p += alignup((size_t)N * HID_C * 2); // dead after gemm_l1
    u16*   hb         = (u16*)p;   p += alignup((size_t)N * HID_C * 2);
    // alias late-stage buffers onto dead xb/ag1 regions
    u16*   hlb        = xb;                              // N*OUT_C*2 = 12.8 MB
    u16*   hrb        = xb + (size_t)N * OUT_C;          // second half of xb region
    u16*   zb         = ag1;                             // 12.8 MB in ag1 region

    // converts (independent of CSR)
    cvt_x<<<(N * IN_C / 4 + 255) / 256, 256, 0, stream>>>(x, xb, N * IN_C / 4);
    cvt_w<<<192, 256, 0, stream>>>(w1l, w1r, w2l, w2r, Wb1, Wb2);

    // counting-sort CSR build
    hipMemsetAsync(bcur, 0, (size_t)NB * NREP * CSTRIDE * 4, stream);
    const int nblk1 = (E + EPB - 1) / EPB;
    bucket_edges<<<nblk1, 256, 0, stream>>>(ei, bcur, bkt, E, N, nr2);
    sort_bucket<<<NB, 512, 0, stream>>>(bkt, bcur, csr_sorted, row_start, degp,
                                        inv_deg, N, nr2);

    const int rb = (N + 127) / 128;

    // ag1 = mean_agg(xb)
    agg_bf<HID_C, false><<<(N + 15) / 16, 256, 0, stream>>>(xb, nullptr, row_start,
                                                            degp, csr_sorted,
                                                            inv_deg, ag1, N);
    // h = relu([ag1|xb] @ [w1l|w1r].T + b1)
    gemm_l1<<<rb, 256, 0, stream>>>(ag1, xb, Wb1, b1, hb, N);

    // hl = h@w2l.T ; hr = h@w2r.T + b2
    gemm_mfma<HID_C, OUT_C><<<rb, 256, 0, stream>>>(hb, Wb2, b2, hlb, hrb, N);
    // z = agg(hl)/deg + hr  (bf16)
    agg_bf<OUT_C, true><<<(N + 31) / 32, 256, 0, stream>>>(hlb, hrb, row_start,
                                                           degp, csr_sorted,
                                                           inv_deg, zb, N);

    // decode (bf16 z)
    decode<<<((size_t)E * 8 + 255) / 256, 256, 0, stream>>>(zb, ei, out, E, N);
}

// Round 10
// 371.051 us; speedup vs baseline: 1.0126x; 1.0126x over previous
//
#include <hip/hip_runtime.h>

// GraphSAGE link predictor, bf16-MFMA edition.
//   h = relu( mean_agg(x)@w1l.T + b1 + x@w1r.T )
//   z = mean_agg(h)@w2l.T + b2 + h@w2r.T
//   out[e] = dot(z[src[e]], z[dst[e]])
//
// R7-R12: padded-CSR scatter builds all bottomed at ~70-86us on scattered
//     4B store amplification. R13: counting-sort CSR (bucket 256 fine
//     dst-ranges -> LDS counting sort -> dense copy-out): 399 -> 372.5us.
// R14: agg 8-deep grouping REGRESSED (73->76.5, VGPR 24->36, occ 65->59):
//     agg is at the random-gather machine limit, not MLP-limited.
// R15: (a) revert agg to the measured-best 4-deep form. (b) pack bucket
//     entries to ONE u32: src<2^17, dlocal<391<2^9 -> (dlocal<<17)|src.
//     Halves bkt r/w traffic in both build kernels.
//
// edge_index arrives as int32 (harness converts int64 inputs).

#define IN_C      128
#define HID_C     128
#define OUT_C     64
#define NB        256    // fine dst-range buckets (nr2 = ceil(N/NB) = 391 <= 512)
#define NREP      8      // replicas per bucket; rep = blockIdx&7 = XCD id
#define CSTRIDE   16     // ints per cursor slot (64B line, no false sharing)
#define SUBCAP1   1024   // entries per (bucket,rep); mean ~784, +8 sigma
#define SORTG     8192   // global slots per bucket (mean 6250, +24 sigma)
#define SSORT     7168   // LDS sort buffer ints (28 KB)
#define EPB       1024   // phase-1 edges per block

typedef unsigned short u16;
typedef unsigned int u32;
typedef __attribute__((ext_vector_type(8))) __bf16 bf16x8;
typedef __attribute__((ext_vector_type(4))) float f32x4;
typedef __attribute__((ext_vector_type(4))) int i32x4;

__device__ inline u16 f2bf(float f) {                 // RNE f32 -> bf16
    unsigned u = __float_as_uint(f);
    u += 0x7fff + ((u >> 16) & 1);
    return (u16)(u >> 16);
}
__device__ inline float bflo(unsigned v) { return __uint_as_float(v << 16); }
__device__ inline float bfhi(unsigned v) { return __uint_as_float(v & 0xffff0000u); }

// ---------------------------------------------------------------- phase 1: bucket
// Block-radix partition into NB fine dst-range buckets, XCD-private cursors.
// Entry packed: (dlocal << 17) | src  (src < 2^17, dlocal < 391).
__global__ __launch_bounds__(256) void bucket_edges(const int* __restrict__ ei,
                                                    int* __restrict__ bcur,
                                                    u32* __restrict__ bkt,
                                                    int E, int n, int nr2) {
    __shared__ int hist[NB];
    __shared__ int gofs[NB];
    const int tid = threadIdx.x;
    hist[tid] = 0;
    __syncthreads();

    const int rep  = blockIdx.x & (NREP - 1);   // == XCD id (round-robin dispatch)
    const int base = blockIdx.x * EPB + tid * 4;

    i32x4 d4 = {-1, -1, -1, -1}, s4 = {0, 0, 0, 0};
    if (base < E) {   // base%4==0, E%4==0 => full int4 in bounds
        d4 = __builtin_nontemporal_load((const i32x4*)(ei + (size_t)E + base));
        s4 = __builtin_nontemporal_load((const i32x4*)(ei + base));
    }

    int bk[4], rk[4];
#pragma unroll
    for (int j = 0; j < 4; ++j) {
        int d = d4[j], s = s4[j];
        bk[j] = ((unsigned)d < (unsigned)n && (unsigned)s < (unsigned)n)
                    ? (int)((unsigned)d / (unsigned)nr2) : -1;
        if (bk[j] >= 0) rk[j] = atomicAdd(&hist[bk[j]], 1);   // LDS atomic
    }
    __syncthreads();
    // one 64B-private cursor per (bucket,rep): only XCD `rep` ever touches it.
    gofs[tid] = atomicAdd(&bcur[(tid * NREP + rep) * CSTRIDE], hist[tid]);
    __syncthreads();

#pragma unroll
    for (int j = 0; j < 4; ++j) {
        int b = bk[j];
        if (b >= 0) {
            int pos = gofs[b] + rk[j];
            if (pos < SUBCAP1) {
                u32 dl = (u32)(d4[j] - b * nr2);
                bkt[(size_t)(b * NREP + rep) * SUBCAP1 + pos] =
                    (dl << 17) | (u32)s4[j];
            }
        }
    }
}

// ---------------------------------------------------------------- phase 2: sort
// One block per bucket: LDS counting sort -> dense CSR run + row_start/deg.
__global__ __launch_bounds__(512) void sort_bucket(const u32* __restrict__ bkt,
                                                   const int* __restrict__ bcur,
                                                   int* __restrict__ csr_sorted,
                                                   int* __restrict__ row_start,
                                                   int* __restrict__ degp,
                                                   float* __restrict__ inv_deg,
                                                   int n, int nr2) {
    __shared__ int hist[512];
    __shared__ int scanb[512];
    __shared__ int cursor[512];
    __shared__ int ssz[NREP];
    __shared__ int sorted[SSORT];

    const int b   = blockIdx.x;
    const int tid = threadIdx.x;
    const int r0  = b * nr2;
    hist[tid] = 0;
    if (tid < NREP) ssz[tid] = min(bcur[(b * NREP + tid) * CSTRIDE], SUBCAP1);
    __syncthreads();

    // pass A: histogram over local nodes
    for (int r = 0; r < NREP; ++r) {
        const u32* sp = bkt + (size_t)(b * NREP + r) * SUBCAP1;
        const int m = ssz[r];
        for (int i = tid; i < m; i += 512)
            atomicAdd(&hist[sp[i] >> 17], 1);
    }
    __syncthreads();

    // inclusive Hillis-Steele scan over 512 slots
    int v = hist[tid];
    scanb[tid] = v;
    __syncthreads();
    for (int off = 1; off < 512; off <<= 1) {
        int add = (tid >= off) ? scanb[tid - off] : 0;
        __syncthreads();
        scanb[tid] += add;
        __syncthreads();
    }
    const int excl = scanb[tid] - v;
    cursor[tid] = excl;
    const int node = r0 + tid;
    if (tid < nr2 && node < n) {
        row_start[node] = b * SORTG + excl;
        degp[node]      = v;
        inv_deg[node]   = 1.0f / (float)max(v, 1);
    }
    __syncthreads();

    // pass B: LDS scatter of src ids into sorted order
    for (int r = 0; r < NREP; ++r) {
        const u32* sp = bkt + (size_t)(b * NREP + r) * SUBCAP1;
        const int m = ssz[r];
        for (int i = tid; i < m; i += 512) {
            u32 e = sp[i];
            int pos = atomicAdd(&cursor[e >> 17], 1);
            if (pos < SSORT) sorted[pos] = (int)(e & 0x1FFFFu);
        }
    }
    __syncthreads();

    // dense coalesced copy-out
    const int T = min(scanb[511], SSORT);
    int* dst = csr_sorted + (size_t)b * SORTG;
    for (int i = tid; i < T; i += 512) dst[i] = sorted[i];
}

// ---------------------------------------------------------------- converts
__global__ __launch_bounds__(256) void cvt_x(const float* __restrict__ in,
                                             u16* __restrict__ outb, int n4) {
    int i = blockIdx.x * 256 + threadIdx.x;
    if (i >= n4) return;
    float4 v = ((const float4*)in)[i];
    ushort4 o;
    o.x = f2bf(v.x); o.y = f2bf(v.y); o.z = f2bf(v.z); o.w = f2bf(v.w);
    ((ushort4*)outb)[i] = o;
}

// Wb1[c][0:128]=w1l[c], Wb1[c][128:256]=w1r[c]  -> [128][256] bf16
// Wb2 = cat(w2l,w2r)                             -> [128][128] bf16
__global__ __launch_bounds__(256) void cvt_w(const float* __restrict__ w1l,
                                             const float* __restrict__ w1r,
                                             const float* __restrict__ w2l,
                                             const float* __restrict__ w2r,
                                             u16* __restrict__ Wb1,
                                             u16* __restrict__ Wb2) {
    int i = blockIdx.x * 256 + threadIdx.x;
    if (i < 32768) {
        int c = i >> 8, k = i & 255;
        float v = (k < 128) ? w1l[c * 128 + k] : w1r[c * 128 + (k - 128)];
        Wb1[i] = f2bf(v);
    } else if (i < 49152) {
        int j = i - 32768;
        float v = (j < 8192) ? w2l[j] : w2r[j - 8192];
        Wb2[j] = f2bf(v);
    }
}

// ---------------------------------------------------------------- fused layer-1 GEMM
// h = relu([A0|A1] @ W.T + b), A0/A1 [n][128] bf16, W [128][256] bf16 -> h [n][128] bf16
__global__ __launch_bounds__(256) void gemm_l1(const u16* __restrict__ A0,
                                               const u16* __restrict__ A1,
                                               const u16* __restrict__ Wb,
                                               const float* __restrict__ bias,
                                               u16* __restrict__ outp, int nrows) {
    constexpr int K    = 256;
    constexpr int COLS = 128;
    constexpr int KS   = K / 32;             // 8
    constexpr int NCT  = COLS / 16;          // 8
    constexpr int WROW = K + 8;
    __shared__ u16 wl[COLS * WROW];          // 67.6 KB

    const int t = threadIdx.x;
    for (int i = t; i < COLS * (K / 8); i += 256) {
        int r = i >> 5, p = i & 31;
        *(uint4*)&wl[r * WROW + p * 8] = *(const uint4*)&Wb[(size_t)r * K + p * 8];
    }
    __syncthreads();

    const int wv    = t >> 6;
    const int lane  = t & 63;
    const int cl    = lane & 15;
    const int quad  = lane >> 4;
    const int rbase = blockIdx.x * 128 + wv * 32;

    bf16x8 afrag[2][KS];
#pragma unroll
    for (int tile = 0; tile < 2; ++tile) {
        int r = min(rbase + tile * 16 + cl, nrows - 1);
        const u16* s0 = A0 + (size_t)r * 128 + quad * 8;
        const u16* s1 = A1 + (size_t)r * 128 + quad * 8;
#pragma unroll
        for (int ks = 0; ks < 4; ++ks) {
            afrag[tile][ks]     = *(const bf16x8*)(s0 + ks * 32);
            afrag[tile][4 + ks] = *(const bf16x8*)(s1 + ks * 32);
        }
    }

#pragma unroll
    for (int ct = 0; ct < NCT; ++ct) {
        f32x4 acc0 = {0.f, 0.f, 0.f, 0.f};
        f32x4 acc1 = {0.f, 0.f, 0.f, 0.f};
        const u16* wp = &wl[(ct * 16 + cl) * WROW + quad * 8];
#pragma unroll
        for (int ks = 0; ks < KS; ++ks) {
            bf16x8 bfrag = *(const bf16x8*)(wp + ks * 32);
            acc0 = __builtin_amdgcn_mfma_f32_16x16x32_bf16(afrag[0][ks], bfrag, acc0, 0, 0, 0);
            acc1 = __builtin_amdgcn_mfma_f32_16x16x32_bf16(afrag[1][ks], bfrag, acc1, 0, 0, 0);
        }
        int gc = ct * 16 + cl;
        float bv = bias[gc];
#pragma unroll
        for (int tile = 0; tile < 2; ++tile) {
            f32x4 a = tile ? acc1 : acc0;
#pragma unroll
            for (int r = 0; r < 4; ++r) {
                int row = rbase + tile * 16 + quad * 4 + r;
                if (row < nrows)
                    outp[(size_t)row * COLS + gc] = f2bf(fmaxf(a[r] + bv, 0.f));
            }
        }
    }
}

// ---------------------------------------------------------------- dual GEMM (layer 2)
// [outA | outB](bf16) = xb @ Wb.T ; outB += bias. Wb [2*COLS][K] bf16.
template <int K, int COLS>
__global__ __launch_bounds__(256) void gemm_mfma(const u16* __restrict__ xb,
                                                 const u16* __restrict__ Wb,
                                                 const float* __restrict__ bias,
                                                 u16* __restrict__ outA,
                                                 u16* __restrict__ outB,
                                                 int nrows) {
    constexpr int NCOL = 2 * COLS;
    constexpr int NCT  = NCOL / 16;
    constexpr int KS   = K / 32;
    constexpr int WROW = K + 8;
    __shared__ u16 wl[NCOL * WROW];

    const int t = threadIdx.x;
    for (int i = t; i < NCOL * (K / 8); i += 256) {
        int r = i / (K / 8), p = i % (K / 8);
        *(uint4*)&wl[r * WROW + p * 8] = *(const uint4*)&Wb[(size_t)r * K + p * 8];
    }
    __syncthreads();

    const int wv    = t >> 6;
    const int lane  = t & 63;
    const int cl    = lane & 15;
    const int quad  = lane >> 4;
    const int rbase = blockIdx.x * 128 + wv * 32;

    bf16x8 afrag[2][KS];
#pragma unroll
    for (int tile = 0; tile < 2; ++tile) {
        int r = rbase + tile * 16 + cl;
        const u16* src = xb + (size_t)min(r, nrows - 1) * K + quad * 8;
#pragma unroll
        for (int ks = 0; ks < KS; ++ks)
            afrag[tile][ks] = *(const bf16x8*)(src + ks * 32);
    }

#pragma unroll
    for (int ct = 0; ct < NCT; ++ct) {
        f32x4 acc0 = {0.f, 0.f, 0.f, 0.f};
        f32x4 acc1 = {0.f, 0.f, 0.f, 0.f};
        const u16* wp = &wl[(ct * 16 + cl) * WROW + quad * 8];
#pragma unroll
        for (int ks = 0; ks < KS; ++ks) {
            bf16x8 bfrag = *(const bf16x8*)(wp + ks * 32);
            acc0 = __builtin_amdgcn_mfma_f32_16x16x32_bf16(afrag[0][ks], bfrag, acc0, 0, 0, 0);
            acc1 = __builtin_amdgcn_mfma_f32_16x16x32_bf16(afrag[1][ks], bfrag, acc1, 0, 0, 0);
        }
        int gc = ct * 16 + cl;
        bool isA = gc < COLS;
        float bv = isA ? 0.f : bias[gc - COLS];
        u16* dst = isA ? (outA + gc) : (outB + (gc - COLS));
#pragma unroll
        for (int tile = 0; tile < 2; ++tile) {
            f32x4 a = tile ? acc1 : acc0;
#pragma unroll
            for (int r = 0; r < 4; ++r) {
                int row = rbase + tile * 16 + quad * 4 + r;
                if (row < nrows) dst[(size_t)row * COLS] = f2bf(a[r] + bv);
            }
        }
    }
}

// ---------------------------------------------------------------- aggregate
// out[n] = (sum_{s in row} gl[s]) * inv_deg[n]  [+ other[n]] ; bf16 in/out.
// Exact sorted CSR. 4-deep gather grouping (R13 measured-best; R14's 8-deep
// regressed via VGPR/occupancy).
template <int C, bool HAS_OTHER>
__global__ __launch_bounds__(256) void agg_bf(const u16* __restrict__ gl,
                                              const u16* __restrict__ other,
                                              const int* __restrict__ row_start,
                                              const int* __restrict__ degp,
                                              const int* __restrict__ csr_sorted,
                                              const float* __restrict__ inv_deg,
                                              u16* __restrict__ outp, int n) {
    constexpr int G = C / 8;                 // lanes per node
    int t = threadIdx.x;
    int node = blockIdx.x * (256 / G) + t / G;
    int l = t % G;
    if (node >= n) return;

    int deg = degp[node];
    const int* sp = csr_sorted + row_start[node];
    float a[8] = {0.f, 0.f, 0.f, 0.f, 0.f, 0.f, 0.f, 0.f};
    const size_t coff = (size_t)l * 8;
    for (int p0 = 0; p0 < deg; p0 += 4) {
        int kmax = min(4, deg - p0);
        int idx[4];
#pragma unroll
        for (int k = 0; k < 4; ++k) idx[k] = (k < kmax) ? sp[p0 + k] : 0;
        uint4 v[4];
#pragma unroll
        for (int k = 0; k < 4; ++k)
            if (k < kmax) v[k] = *(const uint4*)(gl + (size_t)idx[k] * C + coff);
#pragma unroll
        for (int k = 0; k < 4; ++k)
            if (k < kmax) {
                a[0] += bflo(v[k].x); a[1] += bfhi(v[k].x);
                a[2] += bflo(v[k].y); a[3] += bfhi(v[k].y);
                a[4] += bflo(v[k].z); a[5] += bfhi(v[k].z);
                a[6] += bflo(v[k].w); a[7] += bfhi(v[k].w);
            }
    }
    float id = inv_deg[node];
    float r[8];
    if (HAS_OTHER) {
        uint4 o = *(const uint4*)(other + (size_t)node * C + coff);
        r[0] = fmaf(a[0], id, bflo(o.x)); r[1] = fmaf(a[1], id, bfhi(o.x));
        r[2] = fmaf(a[2], id, bflo(o.y)); r[3] = fmaf(a[3], id, bfhi(o.y));
        r[4] = fmaf(a[4], id, bflo(o.z)); r[5] = fmaf(a[5], id, bfhi(o.z));
        r[6] = fmaf(a[6], id, bflo(o.w)); r[7] = fmaf(a[7], id, bfhi(o.w));
    } else {
#pragma unroll
        for (int j = 0; j < 8; ++j) r[j] = a[j] * id;
    }
    uint4 w;
    w.x = (unsigned)f2bf(r[0]) | ((unsigned)f2bf(r[1]) << 16);
    w.y = (unsigned)f2bf(r[2]) | ((unsigned)f2bf(r[3]) << 16);
    w.z = (unsigned)f2bf(r[4]) | ((unsigned)f2bf(r[5]) << 16);
    w.w = (unsigned)f2bf(r[6]) | ((unsigned)f2bf(r[7]) << 16);
    *(uint4*)(outp + (size_t)node * C + coff) = w;
}

// ---------------------------------------------------------------- decode (bf16 z)
__global__ __launch_bounds__(256) void decode(const u16* __restrict__ z,
                                              const int* __restrict__ ei,
                                              float* __restrict__ out, int E, int n) {
    int t = blockIdx.x * 256 + threadIdx.x;
    int e = t >> 3, l = t & 7;
    if (e >= E) return;
    int s = __builtin_nontemporal_load(ei + e);
    int d = __builtin_nontemporal_load(ei + (size_t)E + e);
    float p = 0.f;
    if ((unsigned)s < (unsigned)n && (unsigned)d < (unsigned)n) {
        uint4 a = *(const uint4*)(z + (size_t)s * OUT_C + l * 8);
        uint4 b = *(const uint4*)(z + (size_t)d * OUT_C + l * 8);
        p  = bflo(a.x) * bflo(b.x) + bfhi(a.x) * bfhi(b.x);
        p += bflo(a.y) * bflo(b.y) + bfhi(a.y) * bfhi(b.y);
        p += bflo(a.z) * bflo(b.z) + bfhi(a.z) * bfhi(b.z);
        p += bflo(a.w) * bflo(b.w) + bfhi(a.w) * bfhi(b.w);
    }
    p += __shfl_xor(p, 4);
    p += __shfl_xor(p, 2);
    p += __shfl_xor(p, 1);
    if (l == 0) out[e] = p;
}

// ---------------------------------------------------------------- launch
extern "C" void kernel_launch(void* const* d_in, const int* in_sizes, int n_in,
                              void* d_out, int out_size, void* d_ws, size_t ws_size,
                              hipStream_t stream) {
    const float* x   = (const float*)d_in[0];
    const int*   ei  = (const int*)d_in[1];
    const float* w1l = (const float*)d_in[2];
    const float* w1r = (const float*)d_in[3];
    const float* b1  = (const float*)d_in[4];
    const float* w2l = (const float*)d_in[5];
    const float* w2r = (const float*)d_in[6];
    const float* b2  = (const float*)d_in[7];
    float*       out = (float*)d_out;

    const int N = in_sizes[0] / IN_C;
    const int E = in_sizes[1] / 2;
    const int nr2 = (N + NB - 1) / NB;     // nodes per bucket (391)

    auto alignup = [](size_t v) { return (v + 255) & ~(size_t)255; };
    char* p = (char*)d_ws;
    float* inv_deg    = (float*)p; p += alignup((size_t)N * 4);
    int*   degp       = (int*)p;   p += alignup((size_t)N * 4);
    int*   row_start  = (int*)p;   p += alignup((size_t)N * 4);
    int*   bcur       = (int*)p;   p += alignup((size_t)NB * NREP * CSTRIDE * 4);
    int*   csr_sorted = (int*)p;   p += alignup((size_t)NB * SORTG * 4);           // 8.4 MB
    u32*   bkt        = (u32*)p;   p += alignup((size_t)NB * NREP * SUBCAP1 * 4);  // 8.4 MB
    u16*   Wb1        = (u16*)p;   p += alignup((size_t)HID_C * 2 * IN_C * 2);
    u16*   Wb2        = (u16*)p;   p += alignup((size_t)2 * OUT_C * HID_C * 2);
    u16*   xb         = (u16*)p;   p += alignup((size_t)N * IN_C * 2);  // dead after gemm_l1
    u16*   ag1        = (u16*)p;   p += alignup((size_t)N * HID_C * 2); // dead after gemm_l1
    u16*   hb         = (u16*)p;   p += alignup((size_t)N * HID_C * 2);
    // alias late-stage buffers onto dead xb/ag1 regions
    u16*   hlb        = xb;                              // N*OUT_C*2 = 12.8 MB
    u16*   hrb        = xb + (size_t)N * OUT_C;          // second half of xb region
    u16*   zb         = ag1;                             // 12.8 MB in ag1 region

    // converts (independent of CSR)
    cvt_x<<<(N * IN_C / 4 + 255) / 256, 256, 0, stream>>>(x, xb, N * IN_C / 4);
    cvt_w<<<192, 256, 0, stream>>>(w1l, w1r, w2l, w2r, Wb1, Wb2);

    // counting-sort CSR build
    hipMemsetAsync(bcur, 0, (size_t)NB * NREP * CSTRIDE * 4, stream);
    const int nblk1 = (E + EPB - 1) / EPB;
    bucket_edges<<<nblk1, 256, 0, stream>>>(ei, bcur, bkt, E, N, nr2);
    sort_bucket<<<NB, 512, 0, stream>>>(bkt, bcur, csr_sorted, row_start, degp,
                                        inv_deg, N, nr2);

    const int rb = (N + 127) / 128;

    // ag1 = mean_agg(xb)
    agg_bf<HID_C, false><<<(N + 15) / 16, 256, 0, stream>>>(xb, nullptr, row_start,
                                                            degp, csr_sorted,
                                                            inv_deg, ag1, N);
    // h = relu([ag1|xb] @ [w1l|w1r].T + b1)
    gemm_l1<<<rb, 256, 0, stream>>>(ag1, xb, Wb1, b1, hb, N);

    // hl = h@w2l.T ; hr = h@w2r.T + b2
    gemm_mfma<HID_C, OUT_C><<<rb, 256, 0, stream>>>(hb, Wb2, b2, hlb, hrb, N);
    // z = agg(hl)/deg + hr  (bf16)
    agg_bf<OUT_C, true><<<(N + 31) / 32, 256, 0, stream>>>(hlb, hrb, row_start,
                                                           degp, csr_sorted,
                                                           inv_deg, zb, N);

    // decode (bf16 z)
    decode<<<((size_t)E * 8 + 255) / 256, 256, 0, stream>>>(zb, ei, out, E, N);
}